// Round 6
// baseline (151.661 us; speedup 1.0000x reference)
//
#include <hip/hip_runtime.h>
#include <hip/hip_bf16.h>
#include <stdint.h>

#define NB 8
#define HH 128
#define WW 128
#define LL (HH*WW)        // 16384
#define NL (NB*LL)        // 131072

typedef __attribute__((ext_vector_type(8))) short short8;   // 8 bf16
typedef __attribute__((ext_vector_type(4))) float f32x4;

// workspace layout — IDENTICAL to the round-3 passing config
#define WS_COUNTER_OFF 0
#define WS_WT_OFF      256                         // fp32 [b][kk][c][o]
#define WS_WT_FLOATS   (27*4096)
#define WS_LIST_OFF    (WS_WT_OFF + WS_WT_FLOATS*4)  // 442624

__device__ inline short f2bf(float f) {
    __hip_bfloat16 h = __float2bfloat16(f);
    short s; __builtin_memcpy(&s, &h, 2); return s;
}

// ---------------------------------------------------------------------------
// Prep: zero the list counter; transpose weights to wT[b][kk][c][o].
// ---------------------------------------------------------------------------
__global__ __launch_bounds__(256) void prep_kernel(
    const float* __restrict__ w0, const float* __restrict__ w1,
    const float* __restrict__ w2, float* __restrict__ wT,
    unsigned int* __restrict__ counter)
{
    if (blockIdx.x == 0 && threadIdx.x == 0) *counter = 0u;
    int e = blockIdx.x * 256 + threadIdx.x;
    if (e < WS_WT_FLOATS) {
        int b  = e / 36864;            // 9*4096
        int r  = e - b * 36864;
        int kk = r >> 12;
        int q  = r & 4095;
        int c  = q >> 6;
        int o  = q & 63;
        const float* w = (b == 0) ? w0 : ((b == 1) ? w1 : w2);
        wT[e] = w[o * 576 + c * 9 + kk];   // (O,C,3,3) layout
    }
}

// ---------------------------------------------------------------------------
// Masks: one thread per pixel; append sparse-correction items.
// Center tap of branch 1 is always active and handled by the dense kernel.
// ---------------------------------------------------------------------------
__global__ __launch_bounds__(256) void mask_kernel(
    const float* __restrict__ depth, const float* __restrict__ fx,
    unsigned int* __restrict__ counter, unsigned int* __restrict__ list, int cap)
{
    int p = blockIdx.x * 256 + threadIdx.x;
    int n = p >> 14;
    int l = p & (LL - 1);
    int h = l >> 7;
    int w = l & (WW - 1);

    const float* dptr = depth + (n << 14);
    float center = dptr[l];
    float grid = center / fx[n];               // PIXEL_SIZE == 1.0
    float half_ = 0.5f * grid;
    float cpg = center + grid;
    float cmg = center - grid;

    #pragma unroll
    for (int kh = 0; kh < 3; ++kh) {
        int hh = h + kh - 1;
        #pragma unroll
        for (int kw = 0; kw < 3; ++kw) {
            int ww = w + kw - 1;
            int kkid = kh * 3 + kw;
            if (hh < 0 || hh >= HH || ww < 0 || ww >= WW) continue;  // zero-pad
            float d = dptr[(hh << 7) + ww];
            bool m0 = fabsf(d - cpg)    <= half_;
            bool m1 = fabsf(d - center) <= half_;
            bool m2 = fabsf(d - cmg)    <= half_;
            if (kkid == 4) m1 = false;          // dense path covers it
            unsigned bits = (m0 ? 1u : 0u) | (m1 ? 2u : 0u) | (m2 ? 4u : 0u);
            while (bits) {
                int b = __ffs(bits) - 1;
                bits &= bits - 1;
                unsigned pos = atomicAdd(counter, 1u);
                if (pos < (unsigned)cap)
                    list[pos] = ((unsigned)p << 6) | ((unsigned)kkid << 2) | (unsigned)b;
            }
        }
    }
}

// ---------------------------------------------------------------------------
// Dense MFMA: per image, out[64 o][16384 px] = W1c[64x64] * x[64][16384].
// Block = 256 thr = 4 waves, covers 128 px. Each wave: 32 px x 64 o.
// A fragments built in-register from fp32 wT (b=1,kk=4 slice, [c][o]) —
// one-time 64 loads/thread, L2-broadcast. B (x) loaded per 16-px tile as
// 16 independent dwords -> bf16 frags. No LDS, no barriers.
// mfma_f32_16x16x32_bf16 layouts (guide-verified):
//   A: row=lane&15, k=(lane>>4)*8+j ; B: col=lane&15, same k
//   D: col=lane&15, row=(lane>>4)*4+reg
// ---------------------------------------------------------------------------
__global__ __launch_bounds__(256, 4) void dense_mfma_kernel(
    const float* __restrict__ x, const float* __restrict__ wT,
    float* __restrict__ out)
{
    const int lane = threadIdx.x & 63;
    const int wid  = threadIdx.x >> 6;        // 0..3
    const int jcol = lane & 15;
    const int g    = lane >> 4;               // 0..3 (k-group)

    const int b      = blockIdx.x;
    const int n      = b >> 7;                // 128 blocks per image
    const int px_blk = (b & 127) << 7;        // 128 px per block
    const int px_w   = px_blk + (wid << 5);   // 32 px per wave

    // ---- A fragments from wT[b=1][kk=4][c][o]: a[j] = W[o = ot*16+jcol][c] ----
    const float* __restrict__ w13 = wT + 13 * 4096;
    short8 afr[4][2];
    #pragma unroll
    for (int ot = 0; ot < 4; ++ot)
        #pragma unroll
        for (int s = 0; s < 2; ++s) {
            short8 a;
            #pragma unroll
            for (int j = 0; j < 8; ++j) {
                int c = (s << 5) + (g << 3) + j;
                a[j] = f2bf(w13[(c << 6) + (ot << 4) + jcol]);
            }
            afr[ot][s] = a;
        }

    f32x4 acc[4][2];
    #pragma unroll
    for (int ot = 0; ot < 4; ++ot)
        #pragma unroll
        for (int pt = 0; pt < 2; ++pt)
            acc[ot][pt] = (f32x4){0.f, 0.f, 0.f, 0.f};

    const float* __restrict__ xb = x + ((long)n << 20);

    #pragma unroll
    for (int pt = 0; pt < 2; ++pt) {
        const int px = px_w + (pt << 4) + jcol;
        // 16 independent strided loads: c = s*32 + g*8 + j
        float xf[2][8];
        #pragma unroll
        for (int s = 0; s < 2; ++s)
            #pragma unroll
            for (int j = 0; j < 8; ++j)
                xf[s][j] = xb[((long)((s << 5) + (g << 3) + j) << 14) + px];

        short8 bfr[2];
        #pragma unroll
        for (int s = 0; s < 2; ++s)
            #pragma unroll
            for (int j = 0; j < 8; ++j)
                bfr[s][j] = f2bf(xf[s][j]);

        #pragma unroll
        for (int s = 0; s < 2; ++s)
            #pragma unroll
            for (int ot = 0; ot < 4; ++ot)
                acc[ot][pt] = __builtin_amdgcn_mfma_f32_16x16x32_bf16(
                    afr[ot][s], bfr[s], acc[ot][pt], 0, 0, 0);
    }

    // ---- store: o = ot*16 + g*4 + r, px = px_w + pt*16 + jcol ----
    float* __restrict__ ob = out + ((long)n << 20);
    #pragma unroll
    for (int ot = 0; ot < 4; ++ot)
        #pragma unroll
        for (int pt = 0; pt < 2; ++pt)
            #pragma unroll
            for (int r = 0; r < 4; ++r) {
                int o = (ot << 4) + (g << 2) + r;
                ob[((long)o << 14) + px_w + (pt << 4) + jcol] = acc[ot][pt][r];
            }
}

// ---------------------------------------------------------------------------
// Sparse: one wave per list item. lane=c gathers x[n,:,l2] in ONE load ->
// LDS; lane=o consumes via broadcast with L2-hot coalesced weight loads.
// ---------------------------------------------------------------------------
#define SP_BLOCKS 512
__global__ __launch_bounds__(256) void sparse_kernel(
    const float* __restrict__ x, const float* __restrict__ wT,
    float* __restrict__ out,
    const unsigned int* __restrict__ counter,
    const unsigned int* __restrict__ list, int cap)
{
    __shared__ float xs[4][2][64];
    const int lane  = threadIdx.x & 63;
    const int wslot = threadIdx.x >> 6;
    const int wid   = blockIdx.x * 4 + wslot;
    const int nwaves = SP_BLOCKS * 4;

    unsigned cnt = *counter;
    if (cnt > (unsigned)cap) cnt = (unsigned)cap;

    int buf = 0;
    for (unsigned i = (unsigned)wid; i < cnt; i += (unsigned)nwaves, buf ^= 1) {
        unsigned item = list[i];
        int b    = item & 3;
        int kkid = (item >> 2) & 15;
        unsigned p = item >> 6;
        int n = (int)(p >> 14);
        int l = (int)(p & (LL - 1));
        int dh = kkid / 3 - 1, dw = kkid % 3 - 1;
        int l2 = l + dh * WW + dw;               // in-bounds by construction

        xs[wslot][buf][lane] = x[((long)n << 20) + ((long)lane << 14) + l2];

        const float* wt = wT + ((b * 9 + kkid) << 12);   // [c][o]
        const float* xv = xs[wslot][buf];

        float acc = 0.f;
        #pragma unroll 8
        for (int c = 0; c < 64; ++c)
            acc = fmaf(wt[(c << 6) + lane], xv[c], acc);

        atomicAdd(&out[((long)n << 20) + ((long)lane << 14) + l], acc);
    }
}

// ---------------------------------------------------------------------------
extern "C" void kernel_launch(void* const* d_in, const int* in_sizes, int n_in,
                              void* d_out, int out_size, void* d_ws, size_t ws_size,
                              hipStream_t stream)
{
    const float* x     = (const float*)d_in[0];
    const float* depth = (const float*)d_in[1];
    const float* fx    = (const float*)d_in[2];
    const float* w0    = (const float*)d_in[3];
    const float* w1    = (const float*)d_in[4];
    const float* w2    = (const float*)d_in[5];
    float* out = (float*)d_out;

    unsigned char* ws = (unsigned char*)d_ws;
    unsigned int* counter = (unsigned int*)(ws + WS_COUNTER_OFF);
    float*        wT      = (float*)(ws + WS_WT_OFF);
    unsigned int* lst     = (unsigned int*)(ws + WS_LIST_OFF);

    long long cap_ll = ((long long)ws_size - WS_LIST_OFF) / 4;
    if (cap_ll < 0) cap_ll = 0;
    if (cap_ll > (long long)NL * 27) cap_ll = (long long)NL * 27;
    int cap = (int)cap_ll;

    prep_kernel      <<<(WS_WT_FLOATS + 255) / 256, 256, 0, stream>>>(w0, w1, w2, wT, counter);
    mask_kernel      <<<NL / 256, 256, 0, stream>>>(depth, fx, counter, lst, cap);
    dense_mfma_kernel<<<NL / 128, 256, 0, stream>>>(x, wT, out);
    sparse_kernel    <<<SP_BLOCKS, 256, 0, stream>>>(x, wT, out, counter, lst, cap);
}

// Round 9
// 147.425 us; speedup vs baseline: 1.0287x; 1.0287x over previous
//
#include <hip/hip_runtime.h>
#include <hip/hip_bf16.h>
#include <stdint.h>

#define NB 8
#define HH 128
#define WW 128
#define LL (HH*WW)        // 16384
#define NL (NB*LL)        // 131072

typedef __attribute__((ext_vector_type(8))) short short8;   // 8 bf16
typedef __attribute__((ext_vector_type(4))) float f32x4;

// workspace layout (proven good: ws_size = 256 MiB per round-6 fill counters)
#define WS_COUNTER_OFF 0
#define WS_WT_OFF      256                         // fp32 [b][kk][c][o]
#define WS_WT_FLOATS   (27*4096)
#define WS_LIST_OFF    (WS_WT_OFF + WS_WT_FLOATS*4)  // 442624

__device__ inline short f2bf(float f) {
    __hip_bfloat16 h = __float2bfloat16(f);
    short s; __builtin_memcpy(&s, &h, 2); return s;
}

// ---------------------------------------------------------------------------
// Prep: zero the list counter; transpose weights to wT[b][kk][c][o].
// Runs before dense/sparse in stream order, so counter=0 is visible to them.
// ---------------------------------------------------------------------------
__global__ __launch_bounds__(256) void prep_kernel(
    const float* __restrict__ w0, const float* __restrict__ w1,
    const float* __restrict__ w2, float* __restrict__ wT,
    unsigned int* __restrict__ counter)
{
    if (blockIdx.x == 0 && threadIdx.x == 0) *counter = 0u;
    int e = blockIdx.x * 256 + threadIdx.x;
    if (e < WS_WT_FLOATS) {
        int b  = e / 36864;            // 9*4096
        int r  = e - b * 36864;
        int kk = r >> 12;
        int q  = r & 4095;
        int c  = q >> 6;
        int o  = q & 63;
        const float* w = (b == 0) ? w0 : ((b == 1) ? w1 : w2);
        wT[e] = w[o * 576 + c * 9 + kk];   // (O,C,3,3) layout
    }
}

// ---------------------------------------------------------------------------
// Dense MFMA + fused mask. Per image, out[64 o][16384 px] = W1c * x.
// Block = 256 thr = 4 waves, covers 128 px. Threads 0..127 (waves 0,1 —
// wave-uniform split) additionally compute the depth masks for the block's
// 128 pixels and append sparse-correction items.
// A fragments built in-register from fp32 wT (b=1,kk=4 slice, [c][o], L2-hot).
// B (x) loaded per 16-px tile as 16 independent dwords -> bf16 frags.
// mfma_f32_16x16x32_bf16 layouts (guide-verified):
//   A: row=lane&15, k=(lane>>4)*8+j ; B: col=lane&15, same k
//   D: col=lane&15, row=(lane>>4)*4+reg
// ---------------------------------------------------------------------------
__global__ __launch_bounds__(256, 4) void dense_mfma_kernel(
    const float* __restrict__ x, const float* __restrict__ depth,
    const float* __restrict__ fx, const float* __restrict__ wT,
    float* __restrict__ out, unsigned int* __restrict__ counter,
    unsigned int* __restrict__ list, int cap)
{
    const int tid  = threadIdx.x;
    const int lane = tid & 63;
    const int wid  = tid >> 6;                // 0..3
    const int jcol = lane & 15;
    const int g    = lane >> 4;               // 0..3 (k-group)

    const int b      = blockIdx.x;
    const int n      = b >> 7;                // 128 blocks per image
    const int px_blk = (b & 127) << 7;        // 128 px per block
    const int px_w   = px_blk + (wid << 5);   // 32 px per wave

    // ---- fused mask: threads 0..127 handle the block's 128 pixels ----
    if (tid < 128) {
        const int l = px_blk + tid;
        const int p = (n << 14) + l;
        const int h = l >> 7;
        const int w = l & (WW - 1);
        const float* dptr = depth + (n << 14);
        float center = dptr[l];
        float grid = center / fx[n];           // PIXEL_SIZE == 1.0
        float half_ = 0.5f * grid;
        float cpg = center + grid;
        float cmg = center - grid;

        #pragma unroll
        for (int kh = 0; kh < 3; ++kh) {
            int hh = h + kh - 1;
            #pragma unroll
            for (int kw = 0; kw < 3; ++kw) {
                int ww = w + kw - 1;
                int kkid = kh * 3 + kw;
                if (hh < 0 || hh >= HH || ww < 0 || ww >= WW) continue;  // zero-pad
                float d = dptr[(hh << 7) + ww];
                bool m0 = fabsf(d - cpg)    <= half_;
                bool m1 = fabsf(d - center) <= half_;
                bool m2 = fabsf(d - cmg)    <= half_;
                if (kkid == 4) m1 = false;      // dense path covers it
                unsigned bits = (m0 ? 1u : 0u) | (m1 ? 2u : 0u) | (m2 ? 4u : 0u);
                while (bits) {
                    int bb = __ffs(bits) - 1;
                    bits &= bits - 1;
                    unsigned pos = atomicAdd(counter, 1u);
                    if (pos < (unsigned)cap)
                        list[pos] = ((unsigned)p << 6) | ((unsigned)kkid << 2) | (unsigned)bb;
                }
            }
        }
    }

    // ---- A fragments from wT[b=1][kk=4][c][o]: a[j] = W[o = ot*16+jcol][c] ----
    const float* __restrict__ w13 = wT + 13 * 4096;
    short8 afr[4][2];
    #pragma unroll
    for (int ot = 0; ot < 4; ++ot)
        #pragma unroll
        for (int s = 0; s < 2; ++s) {
            short8 a;
            #pragma unroll
            for (int j = 0; j < 8; ++j) {
                int c = (s << 5) + (g << 3) + j;
                a[j] = f2bf(w13[(c << 6) + (ot << 4) + jcol]);
            }
            afr[ot][s] = a;
        }

    f32x4 acc[4][2];
    #pragma unroll
    for (int ot = 0; ot < 4; ++ot)
        #pragma unroll
        for (int pt = 0; pt < 2; ++pt)
            acc[ot][pt] = (f32x4){0.f, 0.f, 0.f, 0.f};

    const float* __restrict__ xb = x + ((long)n << 20);

    #pragma unroll
    for (int pt = 0; pt < 2; ++pt) {
        const int px = px_w + (pt << 4) + jcol;
        // 16 independent strided loads: c = s*32 + g*8 + j
        float xf[2][8];
        #pragma unroll
        for (int s = 0; s < 2; ++s)
            #pragma unroll
            for (int j = 0; j < 8; ++j)
                xf[s][j] = xb[((long)((s << 5) + (g << 3) + j) << 14) + px];

        short8 bfr[2];
        #pragma unroll
        for (int s = 0; s < 2; ++s)
            #pragma unroll
            for (int j = 0; j < 8; ++j)
                bfr[s][j] = f2bf(xf[s][j]);

        #pragma unroll
        for (int s = 0; s < 2; ++s)
            #pragma unroll
            for (int ot = 0; ot < 4; ++ot)
                acc[ot][pt] = __builtin_amdgcn_mfma_f32_16x16x32_bf16(
                    afr[ot][s], bfr[s], acc[ot][pt], 0, 0, 0);
    }

    // ---- store: o = ot*16 + g*4 + r, px = px_w + pt*16 + jcol ----
    float* __restrict__ ob = out + ((long)n << 20);
    #pragma unroll
    for (int ot = 0; ot < 4; ++ot)
        #pragma unroll
        for (int pt = 0; pt < 2; ++pt)
            #pragma unroll
            for (int r = 0; r < 4; ++r) {
                int o = (ot << 4) + (g << 2) + r;
                ob[((long)o << 14) + px_w + (pt << 4) + jcol] = acc[ot][pt][r];
            }
}

// ---------------------------------------------------------------------------
// Sparse: one wave per list item. lane=c gathers x[n,:,l2] in ONE load ->
// LDS; lane=o consumes via broadcast with L2-hot coalesced weight loads.
// ---------------------------------------------------------------------------
#define SP_BLOCKS 512
__global__ __launch_bounds__(256) void sparse_kernel(
    const float* __restrict__ x, const float* __restrict__ wT,
    float* __restrict__ out,
    const unsigned int* __restrict__ counter,
    const unsigned int* __restrict__ list, int cap)
{
    __shared__ float xs[4][2][64];
    const int lane  = threadIdx.x & 63;
    const int wslot = threadIdx.x >> 6;
    const int wid   = blockIdx.x * 4 + wslot;
    const int nwaves = SP_BLOCKS * 4;

    unsigned cnt = *counter;
    if (cnt > (unsigned)cap) cnt = (unsigned)cap;

    int buf = 0;
    for (unsigned i = (unsigned)wid; i < cnt; i += (unsigned)nwaves, buf ^= 1) {
        unsigned item = list[i];
        int b    = item & 3;
        int kkid = (item >> 2) & 15;
        unsigned p = item >> 6;
        int n = (int)(p >> 14);
        int l = (int)(p & (LL - 1));
        int dh = kkid / 3 - 1, dw = kkid % 3 - 1;
        int l2 = l + dh * WW + dw;               // in-bounds by construction

        xs[wslot][buf][lane] = x[((long)n << 20) + ((long)lane << 14) + l2];

        const float* wt = wT + ((b * 9 + kkid) << 12);   // [c][o]
        const float* xv = xs[wslot][buf];

        float acc = 0.f;
        #pragma unroll 8
        for (int c = 0; c < 64; ++c)
            acc = fmaf(wt[(c << 6) + lane], xv[c], acc);

        atomicAdd(&out[((long)n << 20) + ((long)lane << 14) + l], acc);
    }
}

// ---------------------------------------------------------------------------
extern "C" void kernel_launch(void* const* d_in, const int* in_sizes, int n_in,
                              void* d_out, int out_size, void* d_ws, size_t ws_size,
                              hipStream_t stream)
{
    const float* x     = (const float*)d_in[0];
    const float* depth = (const float*)d_in[1];
    const float* fx    = (const float*)d_in[2];
    const float* w0    = (const float*)d_in[3];
    const float* w1    = (const float*)d_in[4];
    const float* w2    = (const float*)d_in[5];
    float* out = (float*)d_out;

    unsigned char* ws = (unsigned char*)d_ws;
    unsigned int* counter = (unsigned int*)(ws + WS_COUNTER_OFF);
    float*        wT      = (float*)(ws + WS_WT_OFF);
    unsigned int* lst     = (unsigned int*)(ws + WS_LIST_OFF);

    long long cap_ll = ((long long)ws_size - WS_LIST_OFF) / 4;
    if (cap_ll < 0) cap_ll = 0;
    if (cap_ll > (long long)NL * 27) cap_ll = (long long)NL * 27;
    int cap = (int)cap_ll;

    prep_kernel      <<<(WS_WT_FLOATS + 255) / 256, 256, 0, stream>>>(w0, w1, w2, wT, counter);
    dense_mfma_kernel<<<NL / 128, 256, 0, stream>>>(x, depth, fx, wT, out, counter, lst, cap);
    sparse_kernel    <<<SP_BLOCKS, 256, 0, stream>>>(x, wT, out, counter, lst, cap);
}

// Round 10
// 145.995 us; speedup vs baseline: 1.0388x; 1.0098x over previous
//
#include <hip/hip_runtime.h>
#include <hip/hip_bf16.h>
#include <stdint.h>

#define NB 8
#define HH 128
#define WW 128
#define LL (HH*WW)        // 16384
#define NL (NB*LL)        // 131072

typedef __attribute__((ext_vector_type(8))) short short8;   // 8 bf16
typedef __attribute__((ext_vector_type(4))) float f32x4;

// workspace layout. ws_size = 256 MiB (proven: round-6 fill counters wrote
// 262144 KB to d_ws), so the extra 8 KB wA region is safely in-bounds.
#define WS_COUNTER_OFF 0
#define WS_WT_OFF      256                            // fp32 [b][kk][c][o]
#define WS_WT_FLOATS   (27*4096)
#define WS_WA_OFF      (WS_WT_OFF + WS_WT_FLOATS*4)   // bf16 [64 o][64 c] w1 center
#define WS_LIST_OFF    (WS_WA_OFF + 8192)

__device__ inline short f2bf(float f) {
    __hip_bfloat16 h = __float2bfloat16(f);
    short s; __builtin_memcpy(&s, &h, 2); return s;
}

// async global->LDS, 16 B per lane, dest = uniform base + lane*16 (HW rule)
__device__ __forceinline__ void async_copy16(float* lds, const float* g) {
    __builtin_amdgcn_global_load_lds(
        (const __attribute__((address_space(1))) unsigned int*)g,
        (__attribute__((address_space(3))) unsigned int*)lds, 16, 0, 0);
}

// ---------------------------------------------------------------------------
// Prep: zero counter; wT fp32 [b][kk][c][o] (sparse); wA bf16 [o][c] (dense A).
// ---------------------------------------------------------------------------
__global__ __launch_bounds__(256) void prep_kernel(
    const float* __restrict__ w0, const float* __restrict__ w1,
    const float* __restrict__ w2, float* __restrict__ wT,
    short* __restrict__ wA, unsigned int* __restrict__ counter)
{
    if (blockIdx.x == 0 && threadIdx.x == 0) *counter = 0u;
    int e = blockIdx.x * 256 + threadIdx.x;
    if (e < WS_WT_FLOATS) {
        int b  = e / 36864;            // 9*4096
        int r  = e - b * 36864;
        int kk = r >> 12;
        int q  = r & 4095;
        int c  = q >> 6;
        int o  = q & 63;
        const float* w = (b == 0) ? w0 : ((b == 1) ? w1 : w2);
        wT[e] = w[o * 576 + c * 9 + kk];   // (O,C,3,3) layout
    }
    if (e < 4096) {                        // wA[o][c] = w1[o][c][1][1]
        int o = e >> 6, c = e & 63;
        wA[e] = f2bf(w1[o * 576 + c * 9 + 4]);
    }
}

// ---------------------------------------------------------------------------
// Dense MFMA + fused mask, async-staged.
// Block = 256 thr = 4 waves, tile = 128 px x 64 c fp32 in LDS (32 KB, linear
// [c][128px] so global_load_lds dest stays contiguous). Wave w stages c rows
// 16w..16w+15 (8 x 1 KB fire-and-forget). Threads 0..127 compute depth masks
// meanwhile. One barrier, then per-lane ds_read gathers -> bf16 frags ->
// 16 x mfma_f32_16x16x32_bf16 per wave (32 px x 64 o).
//   A: row=lane&15, k=(lane>>4)*8+j ; B: col=lane&15, same k
//   D: col=lane&15, row=(lane>>4)*4+reg   (guide-verified)
// ---------------------------------------------------------------------------
__global__ __launch_bounds__(256, 4) void dense_mfma_kernel(
    const float* __restrict__ x, const float* __restrict__ depth,
    const float* __restrict__ fx, const short* __restrict__ wA,
    float* __restrict__ out, unsigned int* __restrict__ counter,
    unsigned int* __restrict__ list, int cap)
{
    __shared__ float tile[64][128];          // [c][px], 32 KB, linear

    const int tid  = threadIdx.x;
    const int lane = tid & 63;
    const int wid  = tid >> 6;               // 0..3
    const int jcol = lane & 15;
    const int g    = lane >> 4;              // 0..3

    const int b      = blockIdx.x;
    const int n      = b >> 7;               // 128 blocks per image
    const int px_blk = (b & 127) << 7;       // 128 px per block

    const float* __restrict__ xb = x + ((long)n << 20);

    // ---- async stage: wave w -> c rows [16w, 16w+16), 8 x 1 KB ----
    {
        const int c0w = wid << 4;
        const int l5  = lane >> 5;           // 0/1: second row of the pair
        const int q4  = (lane & 31) << 2;    // px offset 0..124
        #pragma unroll
        for (int i = 0; i < 8; ++i) {
            const int c0 = c0w + (i << 1);
            const float* src = xb + ((long)(c0 + l5) << 14) + px_blk + q4;
            async_copy16(&tile[c0][0], src);
        }
    }

    // ---- A fragments from bf16 wA[o][c]: 8 x 16 B, L2-hot ----
    short8 afr[4][2];
    #pragma unroll
    for (int ot = 0; ot < 4; ++ot)
        #pragma unroll
        for (int s = 0; s < 2; ++s)
            afr[ot][s] = *(const short8*)(wA + (((ot << 4) + jcol) << 6) + (s << 5) + (g << 3));

    // ---- fused mask: threads 0..127 handle the block's 128 pixels ----
    if (tid < 128) {
        const int l = px_blk + tid;
        const int p = (n << 14) + l;
        const int h = l >> 7;
        const int w = l & (WW - 1);
        const float* dptr = depth + (n << 14);
        float center = dptr[l];
        float grid = center / fx[n];          // PIXEL_SIZE == 1.0
        float half_ = 0.5f * grid;
        float cpg = center + grid;
        float cmg = center - grid;

        #pragma unroll
        for (int kh = 0; kh < 3; ++kh) {
            int hh = h + kh - 1;
            #pragma unroll
            for (int kw = 0; kw < 3; ++kw) {
                int ww = w + kw - 1;
                int kkid = kh * 3 + kw;
                if (hh < 0 || hh >= HH || ww < 0 || ww >= WW) continue;  // zero-pad
                float d = dptr[(hh << 7) + ww];
                bool m0 = fabsf(d - cpg)    <= half_;
                bool m1 = fabsf(d - center) <= half_;
                bool m2 = fabsf(d - cmg)    <= half_;
                if (kkid == 4) m1 = false;     // dense path covers it
                unsigned bits = (m0 ? 1u : 0u) | (m1 ? 2u : 0u) | (m2 ? 4u : 0u);
                while (bits) {
                    int bb = __ffs(bits) - 1;
                    bits &= bits - 1;
                    unsigned pos = atomicAdd(counter, 1u);
                    if (pos < (unsigned)cap)
                        list[pos] = ((unsigned)p << 6) | ((unsigned)kkid << 2) | (unsigned)bb;
                }
            }
        }
    }

    __syncthreads();   // drains global_load_lds (compiler emits vmcnt(0))

    // ---- B frags from LDS + MFMA: wave computes px [32w, 32w+32) x 64 o ----
    f32x4 acc[4][2];
    #pragma unroll
    for (int ot = 0; ot < 4; ++ot)
        #pragma unroll
        for (int pt = 0; pt < 2; ++pt)
            acc[ot][pt] = (f32x4){0.f, 0.f, 0.f, 0.f};

    const int pxw = wid << 5;                 // wave's local px base
    #pragma unroll
    for (int pt = 0; pt < 2; ++pt) {
        const int pl = pxw + (pt << 4) + jcol;   // local px 0..127
        short8 bfr[2];
        #pragma unroll
        for (int s = 0; s < 2; ++s) {
            short8 bb;
            #pragma unroll
            for (int j = 0; j < 8; ++j) {
                int c = (s << 5) + (g << 3) + j;
                bb[j] = f2bf(tile[c][pl]);
            }
            bfr[s] = bb;
        }
        #pragma unroll
        for (int s = 0; s < 2; ++s)
            #pragma unroll
            for (int ot = 0; ot < 4; ++ot)
                acc[ot][pt] = __builtin_amdgcn_mfma_f32_16x16x32_bf16(
                    afr[ot][s], bfr[s], acc[ot][pt], 0, 0, 0);
    }

    // ---- store: o = ot*16 + g*4 + r, px = px_blk + pxw + pt*16 + jcol ----
    float* __restrict__ ob = out + ((long)n << 20);
    #pragma unroll
    for (int ot = 0; ot < 4; ++ot)
        #pragma unroll
        for (int pt = 0; pt < 2; ++pt)
            #pragma unroll
            for (int r = 0; r < 4; ++r) {
                int o = (ot << 4) + (g << 2) + r;
                ob[((long)o << 14) + px_blk + pxw + (pt << 4) + jcol] = acc[ot][pt][r];
            }
}

// ---------------------------------------------------------------------------
// Sparse: one wave per list item. lane=c gathers x[n,:,l2] in ONE load ->
// LDS; lane=o consumes via broadcast with L2-hot coalesced weight loads.
// ---------------------------------------------------------------------------
#define SP_BLOCKS 512
__global__ __launch_bounds__(256) void sparse_kernel(
    const float* __restrict__ x, const float* __restrict__ wT,
    float* __restrict__ out,
    const unsigned int* __restrict__ counter,
    const unsigned int* __restrict__ list, int cap)
{
    __shared__ float xs[4][2][64];
    const int lane  = threadIdx.x & 63;
    const int wslot = threadIdx.x >> 6;
    const int wid   = blockIdx.x * 4 + wslot;
    const int nwaves = SP_BLOCKS * 4;

    unsigned cnt = *counter;
    if (cnt > (unsigned)cap) cnt = (unsigned)cap;

    int buf = 0;
    for (unsigned i = (unsigned)wid; i < cnt; i += (unsigned)nwaves, buf ^= 1) {
        unsigned item = list[i];
        int b    = item & 3;
        int kkid = (item >> 2) & 15;
        unsigned p = item >> 6;
        int n = (int)(p >> 14);
        int l = (int)(p & (LL - 1));
        int dh = kkid / 3 - 1, dw = kkid % 3 - 1;
        int l2 = l + dh * WW + dw;               // in-bounds by construction

        xs[wslot][buf][lane] = x[((long)n << 20) + ((long)lane << 14) + l2];

        const float* wt = wT + ((b * 9 + kkid) << 12);   // [c][o]
        const float* xv = xs[wslot][buf];

        float acc = 0.f;
        #pragma unroll 8
        for (int c = 0; c < 64; ++c)
            acc = fmaf(wt[(c << 6) + lane], xv[c], acc);

        atomicAdd(&out[((long)n << 20) + ((long)lane << 14) + l], acc);
    }
}

// ---------------------------------------------------------------------------
extern "C" void kernel_launch(void* const* d_in, const int* in_sizes, int n_in,
                              void* d_out, int out_size, void* d_ws, size_t ws_size,
                              hipStream_t stream)
{
    const float* x     = (const float*)d_in[0];
    const float* depth = (const float*)d_in[1];
    const float* fx    = (const float*)d_in[2];
    const float* w0    = (const float*)d_in[3];
    const float* w1    = (const float*)d_in[4];
    const float* w2    = (const float*)d_in[5];
    float* out = (float*)d_out;

    unsigned char* ws = (unsigned char*)d_ws;
    unsigned int* counter = (unsigned int*)(ws + WS_COUNTER_OFF);
    float*        wT      = (float*)(ws + WS_WT_OFF);
    short*        wA      = (short*)(ws + WS_WA_OFF);
    unsigned int* lst     = (unsigned int*)(ws + WS_LIST_OFF);

    long long cap_ll = ((long long)ws_size - WS_LIST_OFF) / 4;
    if (cap_ll < 0) cap_ll = 0;
    if (cap_ll > (long long)NL * 27) cap_ll = (long long)NL * 27;
    int cap = (int)cap_ll;

    prep_kernel      <<<(WS_WT_FLOATS + 255) / 256, 256, 0, stream>>>(w0, w1, w2, wT, wA, counter);
    dense_mfma_kernel<<<NL / 128, 256, 0, stream>>>(x, depth, fx, wA, out, counter, lst, cap);
    sparse_kernel    <<<SP_BLOCKS, 256, 0, stream>>>(x, wT, out, counter, lst, cap);
}

// Round 13
// 122.685 us; speedup vs baseline: 1.2362x; 1.1900x over previous
//
#include <hip/hip_runtime.h>
#include <hip/hip_bf16.h>
#include <stdint.h>

#define NB 8
#define HH 128
#define WW 128
#define LL (HH*WW)        // 16384
#define NL (NB*LL)        // 131072

typedef __attribute__((ext_vector_type(8))) short short8;   // 8 bf16
typedef __attribute__((ext_vector_type(4))) float f32x4;

// workspace layout (ws_size = 256 MiB, proven by round-6 fill counters)
#define WS_WT_OFF      256                            // fp32 [b][kk][c][o]
#define WS_WT_FLOATS   (27*4096)
#define WS_WA_OFF      (WS_WT_OFF + WS_WT_FLOATS*4)   // bf16 [64 o][64 c] w1 center
#define WS_CNT_OFF     (WS_WA_OFF + 8192)             // 2048 x u32 per-segment counts
#define WS_LIST_OFF    (WS_CNT_OFF + 8192)            // 1024 blocks x 3456 slots
#define SEG_SLOTS      1728                           // worst case 64 px x 27
#define BLK_SLOTS      (2*SEG_SLOTS)

__device__ inline short f2bf(float f) {
    __hip_bfloat16 h = __float2bfloat16(f);
    short s; __builtin_memcpy(&s, &h, 2); return s;
}

// async global->LDS, 16 B per lane, dest = uniform base + lane*16 (HW rule)
__device__ __forceinline__ void async_copy16(float* lds, const float* g) {
    __builtin_amdgcn_global_load_lds(
        (const __attribute__((address_space(1))) unsigned int*)g,
        (__attribute__((address_space(3))) unsigned int*)lds, 16, 0, 0);
}

// ---------------------------------------------------------------------------
// Prep: wT fp32 [b][kk][c][o] (sparse); wA bf16 [o][c] (dense A). No counter.
// ---------------------------------------------------------------------------
__global__ __launch_bounds__(256) void prep_kernel(
    const float* __restrict__ w0, const float* __restrict__ w1,
    const float* __restrict__ w2, float* __restrict__ wT,
    short* __restrict__ wA)
{
    int e = blockIdx.x * 256 + threadIdx.x;
    if (e < WS_WT_FLOATS) {
        int b  = e / 36864;            // 9*4096
        int r  = e - b * 36864;
        int kk = r >> 12;
        int q  = r & 4095;
        int c  = q >> 6;
        int o  = q & 63;
        const float* w = (b == 0) ? w0 : ((b == 1) ? w1 : w2);
        wT[e] = w[o * 576 + c * 9 + kk];   // (O,C,3,3) layout
    }
    if (e < 4096) {                        // wA[o][c] = w1[o][c][1][1]
        int o = e >> 6, c = e & 63;
        wA[e] = f2bf(w1[o * 576 + c * 9 + 4]);
    }
}

// ---------------------------------------------------------------------------
// Dense MFMA + fused mask, async-staged, ATOMIC-FREE list emission.
// Block = 256 thr = 4 waves, tile = 128 px x 64 c fp32 in LDS (32 KB linear).
// Waves 0,1 compute depth masks for their 64 px each and emit items into a
// private per-(block,wave) list segment via convergent ballot prefix sums.
// MFMA part identical to round 10 (verified).
// ---------------------------------------------------------------------------
__global__ __launch_bounds__(256, 4) void dense_mfma_kernel(
    const float* __restrict__ x, const float* __restrict__ depth,
    const float* __restrict__ fx, const short* __restrict__ wA,
    float* __restrict__ out, unsigned int* __restrict__ cnt,
    unsigned int* __restrict__ list)
{
    __shared__ float tile[64][128];          // [c][px], 32 KB, linear

    const int tid  = threadIdx.x;
    const int lane = tid & 63;
    const int wid  = tid >> 6;               // 0..3
    const int jcol = lane & 15;
    const int g    = lane >> 4;              // 0..3

    const int b      = blockIdx.x;
    const int n      = b >> 7;               // 128 blocks per image
    const int px_blk = (b & 127) << 7;       // 128 px per block

    const float* __restrict__ xb = x + ((long)n << 20);

    // ---- async stage: wave w -> c rows [16w, 16w+16), 8 x 1 KB ----
    {
        const int c0w = wid << 4;
        const int l5  = lane >> 5;           // 0/1: second row of the pair
        const int q4  = (lane & 31) << 2;    // px offset 0..124
        #pragma unroll
        for (int i = 0; i < 8; ++i) {
            const int c0 = c0w + (i << 1);
            const float* src = xb + ((long)(c0 + l5) << 14) + px_blk + q4;
            async_copy16(&tile[c0][0], src);
        }
    }

    // ---- A fragments from bf16 wA[o][c]: 8 x 16 B, L2-hot ----
    short8 afr[4][2];
    #pragma unroll
    for (int ot = 0; ot < 4; ++ot)
        #pragma unroll
        for (int s = 0; s < 2; ++s)
            afr[ot][s] = *(const short8*)(wA + (((ot << 4) + jcol) << 6) + (s << 5) + (g << 3));

    // ---- fused mask, waves 0,1: convergent ballot emission, NO atomics ----
    if (wid < 2) {
        const int l = px_blk + (wid << 6) + lane;
        const int p = (n << 14) + l;
        const int h = l >> 7;
        const int w = l & (WW - 1);
        const float* dptr = depth + (n << 14);
        float center = dptr[l];
        float grid = center / fx[n];          // PIXEL_SIZE == 1.0
        float half_ = 0.5f * grid;
        float cpg = center + grid;
        float cmg = center - grid;

        unsigned int* seg = list + (unsigned)b * BLK_SLOTS + (unsigned)wid * SEG_SLOTS;
        int base = 0;
        const unsigned long long lt = (1ull << lane) - 1ull;

        #pragma unroll
        for (int kh = 0; kh < 3; ++kh) {
            int hh = h + kh - 1;
            #pragma unroll
            for (int kw = 0; kw < 3; ++kw) {
                int ww = w + kw - 1;
                int kkid = kh * 3 + kw;
                bool inb = (hh >= 0) & (hh < HH) & (ww >= 0) & (ww < WW);
                int hc = hh < 0 ? 0 : (hh > 127 ? 127 : hh);
                int wc = ww < 0 ? 0 : (ww > 127 ? 127 : ww);
                float d = dptr[(hc << 7) + wc];   // clamped, always safe
                bool m[3];
                m[0] = inb && (fabsf(d - cpg)    <= half_);
                m[1] = inb && (fabsf(d - center) <= half_) && (kkid != 4);
                m[2] = inb && (fabsf(d - cmg)    <= half_);
                #pragma unroll
                for (int br = 0; br < 3; ++br) {
                    unsigned long long bal = __ballot(m[br]);
                    if (m[br]) {
                        int slot = base + (int)__popcll(bal & lt);
                        seg[slot] = ((unsigned)p << 6) | ((unsigned)kkid << 2) | (unsigned)br;
                    }
                    base += (int)__popcll(bal);
                }
            }
        }
        if (lane == 0) cnt[(b << 1) + wid] = (unsigned)base;
    }

    __syncthreads();   // drains global_load_lds (compiler emits vmcnt(0))

    // ---- B frags from LDS + MFMA: wave computes px [32w, 32w+32) x 64 o ----
    f32x4 acc[4][2];
    #pragma unroll
    for (int ot = 0; ot < 4; ++ot)
        #pragma unroll
        for (int pt = 0; pt < 2; ++pt)
            acc[ot][pt] = (f32x4){0.f, 0.f, 0.f, 0.f};

    const int pxw = wid << 5;                 // wave's local px base
    #pragma unroll
    for (int pt = 0; pt < 2; ++pt) {
        const int pl = pxw + (pt << 4) + jcol;   // local px 0..127
        short8 bfr[2];
        #pragma unroll
        for (int s = 0; s < 2; ++s) {
            short8 bb;
            #pragma unroll
            for (int j = 0; j < 8; ++j) {
                int c = (s << 5) + (g << 3) + j;
                bb[j] = f2bf(tile[c][pl]);
            }
            bfr[s] = bb;
        }
        #pragma unroll
        for (int s = 0; s < 2; ++s)
            #pragma unroll
            for (int ot = 0; ot < 4; ++ot)
                acc[ot][pt] = __builtin_amdgcn_mfma_f32_16x16x32_bf16(
                    afr[ot][s], bfr[s], acc[ot][pt], 0, 0, 0);
    }

    // ---- store: o = ot*16 + g*4 + r, px = px_blk + pxw + pt*16 + jcol ----
    float* __restrict__ ob = out + ((long)n << 20);
    #pragma unroll
    for (int ot = 0; ot < 4; ++ot)
        #pragma unroll
        for (int pt = 0; pt < 2; ++pt)
            #pragma unroll
            for (int r = 0; r < 4; ++r) {
                int o = (ot << 4) + (g << 2) + r;
                ob[((long)o << 14) + px_blk + pxw + (pt << 4) + jcol] = acc[ot][pt][r];
            }
}

// ---------------------------------------------------------------------------
// Sparse: 512 blocks x 4 waves = 2048 waves, 1:1 with the 2048 segments.
// Per item: lane=c gathers x[n,:,l2] in ONE load -> LDS; lane=o consumes via
// broadcast with L2-hot coalesced weight loads; scattered atomicAdd to out.
// ---------------------------------------------------------------------------
#define SP_BLOCKS 512
__global__ __launch_bounds__(256) void sparse_kernel(
    const float* __restrict__ x, const float* __restrict__ wT,
    float* __restrict__ out,
    const unsigned int* __restrict__ cnt,
    const unsigned int* __restrict__ list)
{
    __shared__ float xs[4][2][64];
    const int lane  = threadIdx.x & 63;
    const int wslot = threadIdx.x >> 6;
    const int wi    = blockIdx.x * 4 + wslot;      // 0..2047 == segment id

    const unsigned c_ = cnt[wi];
    const unsigned m  = c_ > SEG_SLOTS ? SEG_SLOTS : c_;   // structural bound
    const unsigned int* seg = list + (unsigned)(wi >> 1) * BLK_SLOTS
                                   + (unsigned)(wi & 1) * SEG_SLOTS;

    int buf = 0;
    for (unsigned i = 0; i < m; ++i, buf ^= 1) {
        unsigned item = seg[i];
        int br   = item & 3;
        int kkid = (item >> 2) & 15;
        unsigned p = item >> 6;
        int n = (int)(p >> 14);
        int l = (int)(p & (LL - 1));
        int dh = kkid / 3 - 1, dw = kkid % 3 - 1;
        int l2 = l + dh * WW + dw;               // in-bounds by construction

        xs[wslot][buf][lane] = x[((long)n << 20) + ((long)lane << 14) + l2];

        const float* wt = wT + ((br * 9 + kkid) << 12);   // [c][o]
        const float* xv = xs[wslot][buf];

        float acc = 0.f;
        #pragma unroll 8
        for (int c = 0; c < 64; ++c)
            acc = fmaf(wt[(c << 6) + lane], xv[c], acc);

        atomicAdd(&out[((long)n << 20) + ((long)lane << 14) + l], acc);
    }
}

// ---------------------------------------------------------------------------
extern "C" void kernel_launch(void* const* d_in, const int* in_sizes, int n_in,
                              void* d_out, int out_size, void* d_ws, size_t ws_size,
                              hipStream_t stream)
{
    const float* x     = (const float*)d_in[0];
    const float* depth = (const float*)d_in[1];
    const float* fx    = (const float*)d_in[2];
    const float* w0    = (const float*)d_in[3];
    const float* w1    = (const float*)d_in[4];
    const float* w2    = (const float*)d_in[5];
    float* out = (float*)d_out;

    unsigned char* ws = (unsigned char*)d_ws;
    float*        wT   = (float*)(ws + WS_WT_OFF);
    short*        wA   = (short*)(ws + WS_WA_OFF);
    unsigned int* cnt  = (unsigned int*)(ws + WS_CNT_OFF);
    unsigned int* lst  = (unsigned int*)(ws + WS_LIST_OFF);

    prep_kernel      <<<(WS_WT_FLOATS + 255) / 256, 256, 0, stream>>>(w0, w1, w2, wT, wA);
    dense_mfma_kernel<<<NL / 128, 256, 0, stream>>>(x, depth, fx, wA, out, cnt, lst);
    sparse_kernel    <<<SP_BLOCKS, 256, 0, stream>>>(x, wT, out, cnt, lst);
}

// Round 14
// 113.404 us; speedup vs baseline: 1.3373x; 1.0818x over previous
//
#include <hip/hip_runtime.h>
#include <hip/hip_bf16.h>
#include <stdint.h>

#define NB 8
#define HH 128
#define WW 128
#define LL (HH*WW)        // 16384
#define NL (NB*LL)        // 131072

typedef __attribute__((ext_vector_type(8))) short short8;   // 8 bf16
typedef __attribute__((ext_vector_type(4))) float f32x4;

// workspace layout (ws_size = 256 MiB, proven by round-6 fill counters)
#define WS_WT_OFF      256                            // fp32 [b][kk][c][o]
#define WS_WT_FLOATS   (27*4096)
#define WS_WA_OFF      (WS_WT_OFF + WS_WT_FLOATS*4)   // bf16 [64 o][64 c] w1 center
#define SEG_SLOTS      1728                           // worst case 64 px x 27

__device__ inline short f2bf(float f) {
    __hip_bfloat16 h = __float2bfloat16(f);
    short s; __builtin_memcpy(&s, &h, 2); return s;
}

// ---------------------------------------------------------------------------
// Prep: wT fp32 [b][kk][c][o] (correction matvecs); wA bf16 [o][c] (dense A).
// ---------------------------------------------------------------------------
__global__ __launch_bounds__(256) void prep_kernel(
    const float* __restrict__ w0, const float* __restrict__ w1,
    const float* __restrict__ w2, float* __restrict__ wT,
    short* __restrict__ wA)
{
    int e = blockIdx.x * 256 + threadIdx.x;
    if (e < WS_WT_FLOATS) {
        int b  = e / 36864;            // 9*4096
        int r  = e - b * 36864;
        int kk = r >> 12;
        int q  = r & 4095;
        int c  = q >> 6;
        int o  = q & 63;
        const float* w = (b == 0) ? w0 : ((b == 1) ? w1 : w2);
        wT[e] = w[o * 576 + c * 9 + kk];   // (O,C,3,3) layout
    }
    if (e < 4096) {                        // wA[o][c] = w1[o][c][1][1]
        int o = e >> 6, c = e & 63;
        wA[e] = f2bf(w1[o * 576 + c * 9 + 4]);
    }
}

// ---------------------------------------------------------------------------
// FUSED kernel: one block = one image row (128 px) of one image.
//  1) waves 0,1: depth-mask scan, emit correction items to an LDS list via
//     convergent ballot prefix sums (no global traffic, no atomics).
//  2) all waves: dense 1x1 MFMA out[64 o][row] = W1c * x[64 c][row], with
//     DIRECT global B-loads (x is L3-resident; verified round-9 path).
//  3) barrier; all 4 waves drain the LDS item list: per item one 64-lane
//     gather of x[n,:,l2], 64x64 matvec, atomicAdd into this block's own
//     out row (row-exclusive => L2-local atomics).
// mfma_f32_16x16x32_bf16 layouts (guide-verified):
//   A: row=lane&15, k=(lane>>4)*8+j ; B: col=lane&15, same k
//   D: col=lane&15, row=(lane>>4)*4+reg
// ---------------------------------------------------------------------------
__global__ __launch_bounds__(256, 6) void fused_kernel(
    const float* __restrict__ x, const float* __restrict__ depth,
    const float* __restrict__ fx, const short* __restrict__ wA,
    const float* __restrict__ wT, float* __restrict__ out)
{
    __shared__ unsigned lds_list[2 * SEG_SLOTS];   // 13.5 KB
    __shared__ unsigned lds_cnt[2];
    __shared__ float    xs[4][64];                 // per-wave gather buffer

    const int tid  = threadIdx.x;
    const int lane = tid & 63;
    const int wid  = tid >> 6;                // 0..3
    const int jcol = lane & 15;
    const int g    = lane >> 4;               // 0..3 (k-group)

    const int b      = blockIdx.x;
    const int n      = b >> 7;                // 128 blocks per image
    const int px_blk = (b & 127) << 7;        // = row h * 128

    const float* __restrict__ xb = x + ((long)n << 20);

    // ---- (1) mask scan, waves 0,1: emit to LDS list ----
    if (wid < 2) {
        const int ll = (wid << 6) + lane;     // block-local pixel 0..127
        const int l  = px_blk + ll;
        const int h  = l >> 7;
        const int w  = l & (WW - 1);
        const float* dptr = depth + (n << 14);
        float center = dptr[l];
        float grid = center / fx[n];          // PIXEL_SIZE == 1.0
        float half_ = 0.5f * grid;
        float cpg = center + grid;
        float cmg = center - grid;

        int base = 0;
        const unsigned long long lt = (1ull << lane) - 1ull;
        unsigned* seg = lds_list + wid * SEG_SLOTS;

        #pragma unroll
        for (int kh = 0; kh < 3; ++kh) {
            int hh = h + kh - 1;
            #pragma unroll
            for (int kw = 0; kw < 3; ++kw) {
                int ww = w + kw - 1;
                int kkid = kh * 3 + kw;
                bool inb = (hh >= 0) & (hh < HH) & (ww >= 0) & (ww < WW);
                int hc = hh < 0 ? 0 : (hh > 127 ? 127 : hh);
                int wc = ww < 0 ? 0 : (ww > 127 ? 127 : ww);
                float d = dptr[(hc << 7) + wc];   // clamped, always safe
                bool m[3];
                m[0] = inb && (fabsf(d - cpg)    <= half_);
                m[1] = inb && (fabsf(d - center) <= half_) && (kkid != 4);
                m[2] = inb && (fabsf(d - cmg)    <= half_);
                #pragma unroll
                for (int br = 0; br < 3; ++br) {
                    unsigned long long bal = __ballot(m[br]);
                    if (m[br]) {
                        int slot = base + (int)__popcll(bal & lt);
                        seg[slot] = ((unsigned)ll << 6) | ((unsigned)kkid << 2) | (unsigned)br;
                    }
                    base += (int)__popcll(bal);
                }
            }
        }
        if (lane == 0) lds_cnt[wid] = (unsigned)base;
    }

    // ---- (2) dense: A frags from wA; B via direct global loads (r9 path) ----
    short8 afr[4][2];
    #pragma unroll
    for (int ot = 0; ot < 4; ++ot)
        #pragma unroll
        for (int s = 0; s < 2; ++s)
            afr[ot][s] = *(const short8*)(wA + (((ot << 4) + jcol) << 6) + (s << 5) + (g << 3));

    f32x4 acc[4][2];
    #pragma unroll
    for (int ot = 0; ot < 4; ++ot)
        #pragma unroll
        for (int pt = 0; pt < 2; ++pt)
            acc[ot][pt] = (f32x4){0.f, 0.f, 0.f, 0.f};

    const int pxw = px_blk + (wid << 5);      // wave's 32-px strip
    #pragma unroll
    for (int pt = 0; pt < 2; ++pt) {
        const int px = pxw + (pt << 4) + jcol;
        float xf[2][8];
        #pragma unroll
        for (int s = 0; s < 2; ++s)
            #pragma unroll
            for (int j = 0; j < 8; ++j)
                xf[s][j] = xb[((long)((s << 5) + (g << 3) + j) << 14) + px];

        short8 bfr[2];
        #pragma unroll
        for (int s = 0; s < 2; ++s)
            #pragma unroll
            for (int j = 0; j < 8; ++j)
                bfr[s][j] = f2bf(xf[s][j]);

        #pragma unroll
        for (int s = 0; s < 2; ++s)
            #pragma unroll
            for (int ot = 0; ot < 4; ++ot)
                acc[ot][pt] = __builtin_amdgcn_mfma_f32_16x16x32_bf16(
                    afr[ot][s], bfr[s], acc[ot][pt], 0, 0, 0);
    }

    float* __restrict__ ob = out + ((long)n << 20);
    #pragma unroll
    for (int ot = 0; ot < 4; ++ot)
        #pragma unroll
        for (int pt = 0; pt < 2; ++pt)
            #pragma unroll
            for (int r = 0; r < 4; ++r) {
                int o = (ot << 4) + (g << 2) + r;
                ob[((long)o << 14) + pxw + (pt << 4) + jcol] = acc[ot][pt][r];
            }

    // ---- (3) drain correction items (stores drained by barrier's vmcnt) ----
    __syncthreads();

    #pragma unroll
    for (int s = 0; s < 2; ++s) {
        const unsigned c_ = lds_cnt[s];
        for (unsigned i = (unsigned)wid; i < c_; i += 4) {
            unsigned item = lds_list[s * SEG_SLOTS + i];
            int br   = item & 3;
            int kkid = (item >> 2) & 15;
            int l    = px_blk + (int)(item >> 6);
            int dh = kkid / 3 - 1, dw = kkid % 3 - 1;
            int l2 = l + dh * WW + dw;            // in-image by construction

            xs[wid][lane] = xb[((long)lane << 14) + l2];   // 64-lane gather

            const float* wt = wT + ((br * 9 + kkid) << 12);   // [c][o], L2-hot
            float a = 0.f;
            #pragma unroll 8
            for (int c = 0; c < 64; ++c)
                a = fmaf(wt[(c << 6) + lane], xs[wid][c], a);

            atomicAdd(&ob[((long)lane << 14) + l], a);    // own row: L2-local
        }
    }
}

// ---------------------------------------------------------------------------
extern "C" void kernel_launch(void* const* d_in, const int* in_sizes, int n_in,
                              void* d_out, int out_size, void* d_ws, size_t ws_size,
                              hipStream_t stream)
{
    const float* x     = (const float*)d_in[0];
    const float* depth = (const float*)d_in[1];
    const float* fx    = (const float*)d_in[2];
    const float* w0    = (const float*)d_in[3];
    const float* w1    = (const float*)d_in[4];
    const float* w2    = (const float*)d_in[5];
    float* out = (float*)d_out;

    unsigned char* ws = (unsigned char*)d_ws;
    float* wT = (float*)(ws + WS_WT_OFF);
    short* wA = (short*)(ws + WS_WA_OFF);

    prep_kernel <<<(WS_WT_FLOATS + 255) / 256, 256, 0, stream>>>(w0, w1, w2, wT, wA);
    fused_kernel<<<NL / 128, 256, 0, stream>>>(x, depth, fx, wA, wT, out);
}